// Round 2
// baseline (599.713 us; speedup 1.0000x reference)
//
#include <hip/hip_runtime.h>

typedef unsigned short u16;
typedef unsigned int u32;
typedef __attribute__((ext_vector_type(4))) float f32x4;
typedef __attribute__((ext_vector_type(8))) short bf16x8;   // 8 bf16 (4 VGPRs), per guide §3
typedef __attribute__((ext_vector_type(4))) float float4v;
typedef __attribute__((ext_vector_type(4))) unsigned short u16x4;
typedef __attribute__((ext_vector_type(8))) unsigned short u16x8;

__device__ __forceinline__ float bf2f(u16 u) { return __uint_as_float(((u32)u) << 16); }
__device__ __forceinline__ u16 f2bf(float f) {
  u32 x = __float_as_uint(f);
  x += 0x7fffu + ((x >> 16) & 1u);   // RNE; values here are finite
  return (u16)(x >> 16);
}

__device__ __forceinline__ void gll16(const void* g, void* l) {
  __builtin_amdgcn_global_load_lds((const __attribute__((address_space(1))) void*)g,
                                   (__attribute__((address_space(3))) void*)l, 16, 0, 0);
}

#define MFMA_BF16(a, b, c) __builtin_amdgcn_mfma_f32_16x16x32_bf16((a), (b), (c), 0, 0, 0)

// ------------------------------- cast fp32 -> bf16 -------------------------------
__global__ __launch_bounds__(256) void cast_kernel(const float* __restrict__ src,
                                                   u16* __restrict__ dst, int n) {
  const int stride = gridDim.x * 256 * 4;
  for (int i = (blockIdx.x * 256 + threadIdx.x) * 4; i < n; i += stride) {
    const float4v v = *(const float4v*)(src + i);
    u16x4 o;
    o[0] = f2bf(v[0]); o[1] = f2bf(v[1]); o[2] = f2bf(v[2]); o[3] = f2bf(v[3]);
    *(u16x4*)(dst + i) = o;
  }
}

// ------------------------------- rope tables -------------------------------
// cos_split[t][j] = cos(t * theta^(-(j&31)/32)), same for sin. (S=2048, 64 cols)
__global__ __launch_bounds__(256) void rope_tables(float* __restrict__ cosd,
                                                   float* __restrict__ sind) {
  const int idx = blockIdx.x * 256 + threadIdx.x;   // 2048*64
  const int t = idx >> 6, j = idx & 63;
  const float inv = powf(10000.0f, -(float)(j & 31) * (1.0f / 32.0f));
  const float ang = (float)t * inv;
  cosd[idx] = cosf(ang);
  sind[idx] = sinf(ang);
}

// ------------------------------- GEMM (C = A * B^T) -------------------------------
// A: [M][lda] bf16, B: [N][ldb] bf16, C[m][n] = sum_k A[m][k]*B[n][k], C: [M][ldc].
// 128x128 tile, BK=64, 4 waves, 16x16x32 MFMA. T2 swizzle via pre-swizzled global src.
__device__ __forceinline__ void store_out(float* C, size_t i, float v) { C[i] = v; }
__device__ __forceinline__ void store_out(u16* C, size_t i, float v) { C[i] = f2bf(v); }

template <typename OutT>
__global__ __launch_bounds__(256) void gemm_bt(const u16* __restrict__ A,
                                               const u16* __restrict__ B,
                                               OutT* __restrict__ C, int M, int N, int K,
                                               int lda, int ldb, int ldc) {
  __shared__ __align__(16) u16 As[128 * 64];
  __shared__ __align__(16) u16 Bs[128 * 64];
  const int nbn = N >> 7;
  const int nwg = gridDim.x;                       // divisible by 8 for all our shapes
  const int wg = (blockIdx.x & 7) * (nwg >> 3) + (blockIdx.x >> 3);  // XCD swizzle (T1)
  const int bm = wg / nbn, bn = wg % nbn;
  const int tid = threadIdx.x;
  const int w = tid >> 6, l = tid & 63, l15 = l & 15, l4 = l >> 4;
  const int wr = w >> 1, wc = w & 1;
  const u16* Abase = A + (size_t)bm * 128 * lda;
  const u16* Bbase = B + (size_t)bn * 128 * ldb;
  f32x4 acc[4][4] = {};

  for (int kt = 0; kt < K; kt += 64) {
    __syncthreads();
    // stage A,B tiles [128][64] bf16 (16KB each): linear LDS dest, swizzled global src
#pragma unroll
    for (int j = 0; j < 4; ++j) {
      const int ib = (w * 4 + j) * 1024;           // wave-uniform instr base (bytes)
      const int o_ = ib + l * 16;                  // this lane's linear LDS byte offset
      const int r = o_ >> 7;                       // row (128B rows)
      const int cb = (o_ & 127) ^ ((r & 7) << 4);  // inverse-swizzled byte-in-row
      gll16(Abase + (size_t)r * lda + kt + (cb >> 1), (char*)As + ib);
      gll16(Bbase + (size_t)r * ldb + kt + (cb >> 1), (char*)Bs + ib);
    }
    __syncthreads();
#pragma unroll
    for (int kk = 0; kk < 2; ++kk) {
      bf16x8 av[4], bv[4];
#pragma unroll
      for (int m = 0; m < 4; ++m) {
        const int R = wr * 64 + m * 16 + l15;
        av[m] = *(const bf16x8*)((const char*)As + R * 128 +
                                 ((kk * 64 + l4 * 16) ^ ((R & 7) << 4)));
      }
#pragma unroll
      for (int n = 0; n < 4; ++n) {
        const int R = wc * 64 + n * 16 + l15;
        bv[n] = *(const bf16x8*)((const char*)Bs + R * 128 +
                                 ((kk * 64 + l4 * 16) ^ ((R & 7) << 4)));
      }
#pragma unroll
      for (int m = 0; m < 4; ++m)
#pragma unroll
        for (int n = 0; n < 4; ++n)
          acc[m][n] = MFMA_BF16(av[m], bv[n], acc[m][n]);
    }
  }
  // epilogue: C/D layout col = lane&15, row = (lane>>4)*4 + reg (m89-verified)
#pragma unroll
  for (int m = 0; m < 4; ++m)
#pragma unroll
    for (int n = 0; n < 4; ++n)
#pragma unroll
      for (int r = 0; r < 4; ++r) {
        const int row = bm * 128 + wr * 64 + m * 16 + l4 * 4 + r;
        const int col = bn * 128 + wc * 64 + n * 16 + l15;
        store_out(C, (size_t)row * ldc + col, acc[m][n][r]);
      }
}

// ------------------------------- rope apply (in place on qkvb) -------------------------------
// qkvb: [8192][6144] bf16. One wave owns one (m,h) slice: reads q/k pairs (2j,2j+1),
// writes rotated values to (j, 64+j). In-wave program order makes this race-free.
__global__ __launch_bounds__(256) void rope_apply_inplace(u16* __restrict__ qkvb,
                                                          const float* __restrict__ cosd,
                                                          const float* __restrict__ sind) {
  const int wid = blockIdx.x * 4 + (threadIdx.x >> 6);  // 8192*16 waves
  const int j = threadIdx.x & 63;
  const int h = wid & 15;
  const int m = wid >> 4;
  const int s = m & 2047;
  const float c = cosd[s * 64 + j];
  const float sn = sind[s * 64 + j];
  u16* qp = qkvb + (size_t)m * 6144 + h * 128;
  u16* kp = qp + 2048;
  const u32 qv = *(const u32*)(qp + 2 * j);
  const u32 kv = *(const u32*)(kp + 2 * j);
  const float q1 = bf2f((u16)(qv & 0xffff)), q2 = bf2f((u16)(qv >> 16));
  const float k1 = bf2f((u16)(kv & 0xffff)), k2 = bf2f((u16)(kv >> 16));
  qp[j]      = f2bf(q1 * c - q2 * sn);
  qp[64 + j] = f2bf(q1 * sn + q2 * c);
  kp[j]      = f2bf(k1 * c - k2 * sn);
  kp[64 + j] = f2bf(k1 * sn + k2 * c);
}

// ------------------------------- V transpose -------------------------------
// reads V part of qkvb, writes vt: [bh=64][d=128][s=2048] bf16 (for contiguous PV B-frags)
__global__ __launch_bounds__(256) void v_transpose(const u16* __restrict__ qkvb,
                                                   u16* __restrict__ vt) {
  __shared__ u16 tile[64][130];                    // +2 pad
  const int st = blockIdx.x & 31, bh = blockIdx.x >> 5;
  const int b = bh >> 4, h = bh & 15;
  const int tid = threadIdx.x;
#pragma unroll
  for (int p = 0; p < 4; ++p) {                    // read 64x128, coalesced
    const int ss = p * 16 + (tid >> 4);
    const int d0 = (tid & 15) * 8;
    const u16x8 v = *(const u16x8*)(qkvb + (size_t)(b * 2048 + st * 64 + ss) * 6144 +
                                    4096 + h * 128 + d0);
#pragma unroll
    for (int i = 0; i < 8; ++i) tile[ss][d0 + i] = v[i];
  }
  __syncthreads();
#pragma unroll
  for (int p = 0; p < 4; ++p) {                    // write 128x64, coalesced
    const int d = p * 32 + (tid >> 3);
    const int s0 = (tid & 7) * 8;
    u16x8 ov;
#pragma unroll
    for (int i = 0; i < 8; ++i) ov[i] = tile[s0 + i][d];
    *(u16x8*)(vt + (size_t)(bh * 128 + d) * 2048 + st * 64 + s0) = ov;
  }
}

// ------------------------------- flash attention -------------------------------
// grid(x=bh=64, y=qt=32). Q,K read from qkvb (row stride 6144); V from vt.
// y written IN PLACE over the q-columns of qkvb (each block writes only the Q slice
// that it alone reads, after loading Q to registers).
__global__ __launch_bounds__(256) void flash_attn(u16* __restrict__ qkvb,
                                                  const u16* __restrict__ vt) {
  const int bh = blockIdx.x, qt = blockIdx.y;
  const int b = bh >> 4, h = bh & 15;
  const int tid = threadIdx.x;
  const int w = tid >> 6, l = tid & 63, l15 = l & 15, l4 = l >> 4;
  __shared__ __align__(16) u16 Ks[64 * 128];       // [key][d], swizzled
  __shared__ __align__(16) u16 Vs[128 * 64];       // [d][key], swizzled
  __shared__ __align__(16) u16 Ps[4][16 * 72];     // per-wave P, stride 72 (pad)

  // Q fragments: wave w owns q rows qt*64 + w*16 + [0,16)
  bf16x8 qf[4];
  const u16* Qp = qkvb + (size_t)(b * 2048 + qt * 64 + w * 16 + l15) * 6144 + h * 128 + l4 * 8;
#pragma unroll
  for (int kk = 0; kk < 4; ++kk) qf[kk] = *(const bf16x8*)(Qp + kk * 32);

  f32x4 o[8] = {};
  float mrun[4] = {-1e30f, -1e30f, -1e30f, -1e30f};
  float lrun[4] = {0.f, 0.f, 0.f, 0.f};
  const u16* Vg0 = vt + (size_t)bh * 128 * 2048;

  for (int kt = 0; kt <= qt; ++kt) {
    __syncthreads();                               // prev tile reads done
    const u16* Kg = qkvb + (size_t)(b * 2048 + kt * 64) * 6144 + 2048 + h * 128;
    const u16* Vg = Vg0 + kt * 64;
#pragma unroll
    for (int j = 0; j < 4; ++j) {
      const int ib = (w * 4 + j) * 1024;
      const int o_ = ib + l * 16;
      {  // K tile: 64 rows x 256B, global row stride 6144 elems
        const int r = o_ >> 8;
        const int cb = (o_ & 255) ^ ((r & 7) << 4);
        gll16(Kg + (size_t)r * 6144 + (cb >> 1), (char*)Ks + ib);
      }
      {  // V tile (transposed source): 128 rows x 128B, global row stride 2048 elems
        const int r = o_ >> 7;
        const int cb = (o_ & 127) ^ ((r & 7) << 4);
        gll16(Vg + (size_t)r * 2048 + (cb >> 1), (char*)Vs + ib);
      }
    }
    __syncthreads();                               // staging drained (vmcnt0 @ barrier)

    // S = Q K^T  (16 q-rows x 64 keys per wave)
    f32x4 s[4] = {};
#pragma unroll
    for (int n = 0; n < 4; ++n) {
      const int R = n * 16 + l15;
#pragma unroll
      for (int kk = 0; kk < 4; ++kk) {
        const bf16x8 kf = *(const bf16x8*)((const char*)Ks + R * 256 +
                                           ((kk * 64 + l4 * 16) ^ ((R & 7) << 4)));
        s[n] = MFMA_BF16(qf[kk], kf, s[n]);
      }
    }
    // scale + causal mask + tile row-max
    const int rowg0 = qt * 64 + w * 16 + l4 * 4;
    float tmax[4] = {-1e30f, -1e30f, -1e30f, -1e30f};
#pragma unroll
    for (int n = 0; n < 4; ++n) {
      const int colg = kt * 64 + n * 16 + l15;
#pragma unroll
      for (int r = 0; r < 4; ++r) {
        float sv = s[n][r] * 0.088388347648318447f;
        sv = (colg > rowg0 + r) ? -1e30f : sv;
        s[n][r] = sv;
        tmax[r] = fmaxf(tmax[r], sv);
      }
    }
#pragma unroll
    for (int r = 0; r < 4; ++r)
#pragma unroll
      for (int d = 1; d < 16; d <<= 1)
        tmax[r] = fmaxf(tmax[r], __shfl_xor(tmax[r], d));
    float alpha[4], rsum[4];
#pragma unroll
    for (int r = 0; r < 4; ++r) {
      const float mnew = fmaxf(mrun[r], tmax[r]);
      alpha[r] = __expf(mrun[r] - mnew);
      mrun[r] = mnew;
      rsum[r] = 0.f;
    }
#pragma unroll
    for (int n = 0; n < 4; ++n)
#pragma unroll
      for (int r = 0; r < 4; ++r) {
        const float p = __expf(s[n][r] - mrun[r]);
        s[n][r] = p;
        rsum[r] += p;
      }
#pragma unroll
    for (int r = 0; r < 4; ++r) {
#pragma unroll
      for (int d = 1; d < 16; d <<= 1) rsum[r] += __shfl_xor(rsum[r], d);
      lrun[r] = lrun[r] * alpha[r] + rsum[r];
    }
#pragma unroll
    for (int dd = 0; dd < 8; ++dd)
#pragma unroll
      for (int r = 0; r < 4; ++r) o[dd][r] *= alpha[r];

    // P -> LDS (score layout row=(l4*4+r), col=n*16+l15), then reread as A-operand
    u16* Pw = &Ps[w][0];
#pragma unroll
    for (int n = 0; n < 4; ++n)
#pragma unroll
      for (int r = 0; r < 4; ++r)
        Pw[(l4 * 4 + r) * 72 + n * 16 + l15] = f2bf(s[n][r]);
    __syncthreads();

    bf16x8 pa[2];
#pragma unroll
    for (int kk = 0; kk < 2; ++kk)
      pa[kk] = *(const bf16x8*)(Pw + l15 * 72 + kk * 32 + l4 * 8);
#pragma unroll
    for (int dd = 0; dd < 8; ++dd) {
      const int R = dd * 16 + l15;
#pragma unroll
      for (int kk = 0; kk < 2; ++kk) {
        const bf16x8 vv = *(const bf16x8*)((const char*)Vs + R * 128 +
                                           ((kk * 64 + l4 * 16) ^ ((R & 7) << 4)));
        o[dd] = MFMA_BF16(pa[kk], vv, o[dd]);
      }
    }
  }

  // epilogue: O /= l, write y over the q-columns of qkvb
  float inv[4];
#pragma unroll
  for (int r = 0; r < 4; ++r) inv[r] = 1.0f / lrun[r];
#pragma unroll
  for (int dd = 0; dd < 8; ++dd)
#pragma unroll
    for (int r = 0; r < 4; ++r) {
      const int row = b * 2048 + qt * 64 + w * 16 + l4 * 4 + r;
      const int col = h * 128 + dd * 16 + l15;
      qkvb[(size_t)row * 6144 + col] = f2bf(o[dd][r] * inv[r]);
    }
}

// ------------------------------- launch -------------------------------
extern "C" void kernel_launch(void* const* d_in, const int* in_sizes, int n_in,
                              void* d_out, int out_size, void* d_ws, size_t ws_size,
                              hipStream_t stream) {
  const float* x     = (const float*)d_in[0];
  // d_in[1] = mask (causal, implemented analytically)
  const float* w_qkv = (const float*)d_in[2];
  const float* w_out = (const float*)d_in[3];
  float* out = (float*)d_out;
  char* ws = (char*)d_ws;

  // Peak workspace: 161 MB (round-0's 289 MB likely overflowed ws_size -> abort).
  u16* woutb = (u16*)(ws);                          // [0,8) MB, live till GEMM2
  u16* xb    = (u16*)(ws + ((size_t)8 << 20));      // [8,40), dead after GEMM1
  u16* vt    = (u16*)(ws + ((size_t)8 << 20));      // [8,40), written after GEMM1
  u16* wqkvb = (u16*)(ws + ((size_t)40 << 20));     // [40,64), dead after GEMM1
  u16* qkvb  = (u16*)(ws + ((size_t)64 << 20));     // [64,160); y lands in q-cols
  float* cosd = (float*)(ws + ((size_t)160 << 20)); // 0.5 MB
  float* sind = (float*)(ws + ((size_t)160 << 20) + ((size_t)1 << 19));

  cast_kernel<<<2048, 256, 0, stream>>>(x, xb, 8192 * 2048);
  cast_kernel<<<2048, 256, 0, stream>>>(w_qkv, wqkvb, 6144 * 2048);
  cast_kernel<<<1024, 256, 0, stream>>>(w_out, woutb, 2048 * 2048);
  rope_tables<<<512, 256, 0, stream>>>(cosd, sind);
  gemm_bt<u16><<<3072, 256, 0, stream>>>(xb, wqkvb, qkvb, 8192, 6144, 2048,
                                         2048, 2048, 6144);
  rope_apply_inplace<<<32768, 256, 0, stream>>>(qkvb, cosd, sind);
  v_transpose<<<2048, 256, 0, stream>>>(qkvb, vt);
  flash_attn<<<dim3(64, 32), 256, 0, stream>>>(qkvb, vt);
  gemm_bt<float><<<1024, 256, 0, stream>>>(qkvb, woutb, out, 8192, 2048, 2048,
                                           6144, 2048, 2048);
}

// Round 3
// 538.755 us; speedup vs baseline: 1.1131x; 1.1131x over previous
//
#include <hip/hip_runtime.h>

typedef unsigned short u16;
typedef unsigned int u32;
typedef __attribute__((ext_vector_type(4))) float f32x4;
typedef __attribute__((ext_vector_type(8))) short bf16x8;   // 8 bf16 (4 VGPRs), per guide §3
typedef __attribute__((ext_vector_type(4))) float float4v;
typedef __attribute__((ext_vector_type(4))) unsigned short u16x4;
typedef __attribute__((ext_vector_type(8))) unsigned short u16x8;

__device__ __forceinline__ float bf2f(u16 u) { return __uint_as_float(((u32)u) << 16); }
__device__ __forceinline__ u16 f2bf(float f) {
  u32 x = __float_as_uint(f);
  x += 0x7fffu + ((x >> 16) & 1u);   // RNE; values here are finite
  return (u16)(x >> 16);
}

__device__ __forceinline__ void gll16(const void* g, void* l) {
  __builtin_amdgcn_global_load_lds((const __attribute__((address_space(1))) void*)g,
                                   (__attribute__((address_space(3))) void*)l, 16, 0, 0);
}

#define MFMA_BF16(a, b, c) __builtin_amdgcn_mfma_f32_16x16x32_bf16((a), (b), (c), 0, 0, 0)

#define BARRIER() __builtin_amdgcn_s_barrier()
#define LGKM0() do { asm volatile("s_waitcnt lgkmcnt(0)" ::: "memory"); \
                     __builtin_amdgcn_sched_barrier(0); } while (0)
#define VMCNT(n) do { asm volatile("s_waitcnt vmcnt(" #n ")" ::: "memory"); \
                      __builtin_amdgcn_sched_barrier(0); } while (0)

// ------------------------------- cast fp32 -> bf16 -------------------------------
__global__ __launch_bounds__(256) void cast_kernel(const float* __restrict__ src,
                                                   u16* __restrict__ dst, int n) {
  const int stride = gridDim.x * 256 * 4;
  for (int i = (blockIdx.x * 256 + threadIdx.x) * 4; i < n; i += stride) {
    const float4v v = *(const float4v*)(src + i);
    u16x4 o;
    o[0] = f2bf(v[0]); o[1] = f2bf(v[1]); o[2] = f2bf(v[2]); o[3] = f2bf(v[3]);
    *(u16x4*)(dst + i) = o;
  }
}

// ------------------------------- rope tables -------------------------------
__global__ __launch_bounds__(256) void rope_tables(float* __restrict__ cosd,
                                                   float* __restrict__ sind) {
  const int idx = blockIdx.x * 256 + threadIdx.x;   // 2048*64
  const int t = idx >> 6, j = idx & 63;
  const float inv = powf(10000.0f, -(float)(j & 31) * (1.0f / 32.0f));
  const float ang = (float)t * inv;
  cosd[idx] = cosf(ang);
  sind[idx] = sinf(ang);
}

// ------------------------------- GEMM 256x256 8-phase (C = A * B^T) -------------------------------
// A: [M][lda] bf16, B: [N][ldb] bf16, C[m][n] = sum_k A[m][k]*B[n][k], C: [M][ldc].
// 8 waves (2Mx4N, interleaved frag tiling), BK=64, double-buffered LDS (128KB),
// snake quadrant phases, counted vmcnt(6), setprio around MFMA (T2+T3+T4+T5).
__device__ __forceinline__ void store_out(float* C, size_t i, float v) { C[i] = v; }
__device__ __forceinline__ void store_out(u16* C, size_t i, float v) { C[i] = f2bf(v); }

#define PH_MFMA(MG, NG)                                                          \
  do {                                                                           \
    _Pragma("unroll") for (int i_ = 0; i_ < 4; ++i_)                             \
      _Pragma("unroll") for (int jn_ = 0; jn_ < 2; ++jn_)                        \
        _Pragma("unroll") for (int ks_ = 0; ks_ < 2; ++ks_)                      \
          acc[(MG) * 4 + i_][(NG) * 2 + jn_] =                                   \
              MFMA_BF16(af[i_][ks_], bfr[jn_][ks_],                              \
                        acc[(MG) * 4 + i_][(NG) * 2 + jn_]);                     \
  } while (0)

template <typename OutT>
__global__ __launch_bounds__(512, 2) void gemm_bt8(const u16* __restrict__ A,
                                                   const u16* __restrict__ B,
                                                   OutT* __restrict__ C, int M, int N, int K,
                                                   int lda, int ldb, int ldc) {
  __shared__ __align__(16) u16 LDS[2][2][2][128 * 64];  // [buf][A=0/B=1][half][128x64]
  const int nbn = N >> 8;
  const int nwg = gridDim.x;                       // divisible by 8 for our shapes
  const int wg = (blockIdx.x & 7) * (nwg >> 3) + (blockIdx.x >> 3);  // XCD swizzle (T1)
  const int bm = wg / nbn, bn = wg % nbn;
  const int tid = threadIdx.x;
  const int w = tid >> 6, l = tid & 63, l15 = l & 15, l4 = l >> 4;
  const int wr = w >> 2, wc = w & 3;               // 2 M-warps x 4 N-warps
  const u16* Abase = A + (size_t)bm * 256 * lda;
  const u16* Bbase = B + (size_t)bn * 256 * ldb;
  const int NT = K >> 6;

  f32x4 acc[8][4] = {};
  bf16x8 af[4][2], bfr[2][2];

  // stage one half-tile [128 rows][64 cols] (16KB): linear LDS dest, inv-swizzled global src
  auto STAGE = [&](int sel, int h, int t) {
    const u16* src = (sel ? Bbase + (size_t)h * 128 * ldb : Abase + (size_t)h * 128 * lda) +
                     t * 64;
    const int ld = sel ? ldb : lda;
    char* dst = (char*)&LDS[t & 1][sel][h][0];
#pragma unroll
    for (int j = 0; j < 2; ++j) {
      const int o = j * 8192 + tid * 16;
      const int r = o >> 7;
      const int cb = (o & 127) ^ ((r & 7) << 4);
      gll16(src + (size_t)r * ld + (cb >> 1), dst + o);
    }
  };
  // ds-load register subtiles (interleaved warp tiling: wave rows i*32+wr*16+l15)
  auto LDA_ = [&](int bb, int mg) {
    const char* base = (const char*)&LDS[bb][0][mg][0];
#pragma unroll
    for (int i = 0; i < 4; ++i) {
      const int R = i * 32 + wr * 16 + l15;
#pragma unroll
      for (int ks = 0; ks < 2; ++ks)
        af[i][ks] = *(const bf16x8*)(base + R * 128 + ((ks * 64 + l4 * 16) ^ ((R & 7) << 4)));
    }
  };
  auto LDB_ = [&](int bb, int ng) {
    const char* base = (const char*)&LDS[bb][1][ng][0];
#pragma unroll
    for (int jn = 0; jn < 2; ++jn) {
      const int R = jn * 64 + wc * 16 + l15;
#pragma unroll
      for (int ks = 0; ks < 2; ++ks)
        bfr[jn][ks] = *(const bf16x8*)(base + R * 128 + ((ks * 64 + l4 * 16) ^ ((R & 7) << 4)));
    }
  };

  // prologue: tile0 (4 half-tiles) + {B0,A1,B1} of tile1; vmcnt(6) completes tile0
  STAGE(0, 0, 0); STAGE(1, 0, 0); STAGE(0, 1, 0); STAGE(1, 1, 0);
  if (NT > 1) { STAGE(1, 0, 1); STAGE(0, 1, 1); STAGE(1, 1, 1); }
  VMCNT(6);
  BARRIER();

  for (int T = 0; T < NT; ++T) {
    const int bb = T & 1;
    // p1 (m0,n0): read A0+B0; stage A0(T+1) -> other buf (freed at T-1 p4)
    LDA_(bb, 0); LDB_(bb, 0);
    if (T + 1 < NT) STAGE(0, 0, T + 1);
    BARRIER(); LGKM0();
    __builtin_amdgcn_s_setprio(1); PH_MFMA(0, 0); __builtin_amdgcn_s_setprio(0);
    BARRIER();
    // p2 (m1,n0): read A1 (B0 reused in regs); stage B0(T+2) over B0 (last read p1)
    LDA_(bb, 1);
    if (T + 2 < NT) STAGE(1, 0, T + 2);
    BARRIER(); LGKM0();
    __builtin_amdgcn_s_setprio(1); PH_MFMA(1, 0); __builtin_amdgcn_s_setprio(0);
    BARRIER();
    // p3 (m1,n1): read B1 (A1 reused); stage A1(T+2) over A1 (last read p2)
    LDB_(bb, 1);
    if (T + 2 < NT) STAGE(0, 1, T + 2);
    BARRIER(); LGKM0();
    __builtin_amdgcn_s_setprio(1); PH_MFMA(1, 1); __builtin_amdgcn_s_setprio(0);
    BARRIER();
    // p4 (m0,n1): re-read A0 (B1 reused); stage B1(T+2) over B1 (last read p3)
    LDA_(bb, 0);
    if (T + 2 < NT) STAGE(1, 1, T + 2);
    BARRIER(); LGKM0();
    __builtin_amdgcn_s_setprio(1); PH_MFMA(0, 1); __builtin_amdgcn_s_setprio(0);
    // K-tile boundary: complete tile T+1 (oldest 8 loads), keep 3 half-tiles in flight
    if (T + 2 < NT) { VMCNT(6); } else { VMCNT(0); }
    BARRIER();
  }

  // epilogue: C/D layout col = lane&15, row = (lane>>4)*4 + reg
#pragma unroll
  for (int mf = 0; mf < 8; ++mf) {
    const int mg = mf >> 2, i = mf & 3;
    const int row0 = bm * 256 + mg * 128 + i * 32 + wr * 16 + l4 * 4;
#pragma unroll
    for (int f = 0; f < 4; ++f) {
      const int col = bn * 256 + f * 64 + wc * 16 + l15;
#pragma unroll
      for (int rr = 0; rr < 4; ++rr)
        store_out(C, (size_t)(row0 + rr) * ldc + col, acc[mf][f][rr]);
    }
  }
}

// ------------------------------- rope apply (in place on qkvb) -------------------------------
__global__ __launch_bounds__(256) void rope_apply_inplace(u16* __restrict__ qkvb,
                                                          const float* __restrict__ cosd,
                                                          const float* __restrict__ sind) {
  const int wid = blockIdx.x * 4 + (threadIdx.x >> 6);  // 8192*16 waves
  const int j = threadIdx.x & 63;
  const int h = wid & 15;
  const int m = wid >> 4;
  const int s = m & 2047;
  const float c = cosd[s * 64 + j];
  const float sn = sind[s * 64 + j];
  u16* qp = qkvb + (size_t)m * 6144 + h * 128;
  u16* kp = qp + 2048;
  const u32 qv = *(const u32*)(qp + 2 * j);
  const u32 kv = *(const u32*)(kp + 2 * j);
  const float q1 = bf2f((u16)(qv & 0xffff)), q2 = bf2f((u16)(qv >> 16));
  const float k1 = bf2f((u16)(kv & 0xffff)), k2 = bf2f((u16)(kv >> 16));
  qp[j]      = f2bf(q1 * c - q2 * sn);
  qp[64 + j] = f2bf(q1 * sn + q2 * c);
  kp[j]      = f2bf(k1 * c - k2 * sn);
  kp[64 + j] = f2bf(k1 * sn + k2 * c);
}

// ------------------------------- V transpose -------------------------------
__global__ __launch_bounds__(256) void v_transpose(const u16* __restrict__ qkvb,
                                                   u16* __restrict__ vt) {
  __shared__ u16 tile[64][130];                    // +2 pad
  const int st = blockIdx.x & 31, bh = blockIdx.x >> 5;
  const int b = bh >> 4, h = bh & 15;
  const int tid = threadIdx.x;
#pragma unroll
  for (int p = 0; p < 4; ++p) {                    // read 64x128, coalesced
    const int ss = p * 16 + (tid >> 4);
    const int d0 = (tid & 15) * 8;
    const u16x8 v = *(const u16x8*)(qkvb + (size_t)(b * 2048 + st * 64 + ss) * 6144 +
                                    4096 + h * 128 + d0);
#pragma unroll
    for (int i = 0; i < 8; ++i) tile[ss][d0 + i] = v[i];
  }
  __syncthreads();
#pragma unroll
  for (int p = 0; p < 4; ++p) {                    // write 128x64, coalesced
    const int d = p * 32 + (tid >> 3);
    const int s0 = (tid & 7) * 8;
    u16x8 ov;
#pragma unroll
    for (int i = 0; i < 8; ++i) ov[i] = tile[s0 + i][d];
    *(u16x8*)(vt + (size_t)(bh * 128 + d) * 2048 + st * 64 + s0) = ov;
  }
}

// ------------------------------- flash attention -------------------------------
__global__ __launch_bounds__(256) void flash_attn(u16* __restrict__ qkvb,
                                                  const u16* __restrict__ vt) {
  const int bh = blockIdx.x, qt = blockIdx.y;
  const int b = bh >> 4, h = bh & 15;
  const int tid = threadIdx.x;
  const int w = tid >> 6, l = tid & 63, l15 = l & 15, l4 = l >> 4;
  __shared__ __align__(16) u16 Ks[64 * 128];       // [key][d], swizzled
  __shared__ __align__(16) u16 Vs[128 * 64];       // [d][key], swizzled
  __shared__ __align__(16) u16 Ps[4][16 * 72];     // per-wave P, stride 72 (pad)

  bf16x8 qf[4];
  const u16* Qp = qkvb + (size_t)(b * 2048 + qt * 64 + w * 16 + l15) * 6144 + h * 128 + l4 * 8;
#pragma unroll
  for (int kk = 0; kk < 4; ++kk) qf[kk] = *(const bf16x8*)(Qp + kk * 32);

  f32x4 o[8] = {};
  float mrun[4] = {-1e30f, -1e30f, -1e30f, -1e30f};
  float lrun[4] = {0.f, 0.f, 0.f, 0.f};
  const u16* Vg0 = vt + (size_t)bh * 128 * 2048;

  for (int kt = 0; kt <= qt; ++kt) {
    __syncthreads();                               // prev tile reads done
    const u16* Kg = qkvb + (size_t)(b * 2048 + kt * 64) * 6144 + 2048 + h * 128;
    const u16* Vg = Vg0 + kt * 64;
#pragma unroll
    for (int j = 0; j < 4; ++j) {
      const int ib = (w * 4 + j) * 1024;
      const int o_ = ib + l * 16;
      {  // K tile: 64 rows x 256B, global row stride 6144 elems
        const int r = o_ >> 8;
        const int cb = (o_ & 255) ^ ((r & 7) << 4);
        gll16(Kg + (size_t)r * 6144 + (cb >> 1), (char*)Ks + ib);
      }
      {  // V tile (transposed source): 128 rows x 128B, global row stride 2048 elems
        const int r = o_ >> 7;
        const int cb = (o_ & 127) ^ ((r & 7) << 4);
        gll16(Vg + (size_t)r * 2048 + (cb >> 1), (char*)Vs + ib);
      }
    }
    __syncthreads();                               // staging drained

    f32x4 s[4] = {};
#pragma unroll
    for (int n = 0; n < 4; ++n) {
      const int R = n * 16 + l15;
#pragma unroll
      for (int kk = 0; kk < 4; ++kk) {
        const bf16x8 kf = *(const bf16x8*)((const char*)Ks + R * 256 +
                                           ((kk * 64 + l4 * 16) ^ ((R & 7) << 4)));
        s[n] = MFMA_BF16(qf[kk], kf, s[n]);
      }
    }
    const int rowg0 = qt * 64 + w * 16 + l4 * 4;
    float tmax[4] = {-1e30f, -1e30f, -1e30f, -1e30f};
#pragma unroll
    for (int n = 0; n < 4; ++n) {
      const int colg = kt * 64 + n * 16 + l15;
#pragma unroll
      for (int r = 0; r < 4; ++r) {
        float sv = s[n][r] * 0.088388347648318447f;
        sv = (colg > rowg0 + r) ? -1e30f : sv;
        s[n][r] = sv;
        tmax[r] = fmaxf(tmax[r], sv);
      }
    }
#pragma unroll
    for (int r = 0; r < 4; ++r)
#pragma unroll
      for (int d = 1; d < 16; d <<= 1)
        tmax[r] = fmaxf(tmax[r], __shfl_xor(tmax[r], d));
    float alpha[4], rsum[4];
#pragma unroll
    for (int r = 0; r < 4; ++r) {
      const float mnew = fmaxf(mrun[r], tmax[r]);
      alpha[r] = __expf(mrun[r] - mnew);
      mrun[r] = mnew;
      rsum[r] = 0.f;
    }
#pragma unroll
    for (int n = 0; n < 4; ++n)
#pragma unroll
      for (int r = 0; r < 4; ++r) {
        const float p = __expf(s[n][r] - mrun[r]);
        s[n][r] = p;
        rsum[r] += p;
      }
#pragma unroll
    for (int r = 0; r < 4; ++r) {
#pragma unroll
      for (int d = 1; d < 16; d <<= 1) rsum[r] += __shfl_xor(rsum[r], d);
      lrun[r] = lrun[r] * alpha[r] + rsum[r];
    }
#pragma unroll
    for (int dd = 0; dd < 8; ++dd)
#pragma unroll
      for (int r = 0; r < 4; ++r) o[dd][r] *= alpha[r];

    u16* Pw = &Ps[w][0];
#pragma unroll
    for (int n = 0; n < 4; ++n)
#pragma unroll
      for (int r = 0; r < 4; ++r)
        Pw[(l4 * 4 + r) * 72 + n * 16 + l15] = f2bf(s[n][r]);
    __syncthreads();

    bf16x8 pa[2];
#pragma unroll
    for (int kk = 0; kk < 2; ++kk)
      pa[kk] = *(const bf16x8*)(Pw + l15 * 72 + kk * 32 + l4 * 8);
#pragma unroll
    for (int dd = 0; dd < 8; ++dd) {
      const int R = dd * 16 + l15;
#pragma unroll
      for (int kk = 0; kk < 2; ++kk) {
        const bf16x8 vv = *(const bf16x8*)((const char*)Vs + R * 128 +
                                           ((kk * 64 + l4 * 16) ^ ((R & 7) << 4)));
        o[dd] = MFMA_BF16(pa[kk], vv, o[dd]);
      }
    }
  }

  float inv[4];
#pragma unroll
  for (int r = 0; r < 4; ++r) inv[r] = 1.0f / lrun[r];
#pragma unroll
  for (int dd = 0; dd < 8; ++dd)
#pragma unroll
    for (int r = 0; r < 4; ++r) {
      const int row = b * 2048 + qt * 64 + w * 16 + l4 * 4 + r;
      const int col = h * 128 + dd * 16 + l15;
      qkvb[(size_t)row * 6144 + col] = f2bf(o[dd][r] * inv[r]);
    }
}

// ------------------------------- launch -------------------------------
extern "C" void kernel_launch(void* const* d_in, const int* in_sizes, int n_in,
                              void* d_out, int out_size, void* d_ws, size_t ws_size,
                              hipStream_t stream) {
  const float* x     = (const float*)d_in[0];
  // d_in[1] = mask (causal, implemented analytically)
  const float* w_qkv = (const float*)d_in[2];
  const float* w_out = (const float*)d_in[3];
  float* out = (float*)d_out;
  char* ws = (char*)d_ws;

  // Peak workspace: 161 MB
  u16* woutb = (u16*)(ws);                          // [0,8) MB, live till GEMM2
  u16* xb    = (u16*)(ws + ((size_t)8 << 20));      // [8,40), dead after GEMM1
  u16* vt    = (u16*)(ws + ((size_t)8 << 20));      // [8,40), written after GEMM1
  u16* wqkvb = (u16*)(ws + ((size_t)40 << 20));     // [40,64), dead after GEMM1
  u16* qkvb  = (u16*)(ws + ((size_t)64 << 20));     // [64,160); y lands in q-cols
  float* cosd = (float*)(ws + ((size_t)160 << 20)); // 0.5 MB
  float* sind = (float*)(ws + ((size_t)160 << 20) + ((size_t)1 << 19));

  cast_kernel<<<2048, 256, 0, stream>>>(x, xb, 8192 * 2048);
  cast_kernel<<<2048, 256, 0, stream>>>(w_qkv, wqkvb, 6144 * 2048);
  cast_kernel<<<1024, 256, 0, stream>>>(w_out, woutb, 2048 * 2048);
  rope_tables<<<512, 256, 0, stream>>>(cosd, sind);
  gemm_bt8<u16><<<768, 512, 0, stream>>>(xb, wqkvb, qkvb, 8192, 6144, 2048,
                                         2048, 2048, 6144);
  rope_apply_inplace<<<32768, 256, 0, stream>>>(qkvb, cosd, sind);
  v_transpose<<<2048, 256, 0, stream>>>(qkvb, vt);
  flash_attn<<<dim3(64, 32), 256, 0, stream>>>(qkvb, vt);
  gemm_bt8<float><<<256, 512, 0, stream>>>(qkvb, woutb, out, 8192, 2048, 2048,
                                           6144, 2048, 2048);
}

// Round 4
// 431.139 us; speedup vs baseline: 1.3910x; 1.2496x over previous
//
#include <hip/hip_runtime.h>

typedef unsigned short u16;
typedef unsigned int u32;
typedef __attribute__((ext_vector_type(4))) float f32x4;
typedef __attribute__((ext_vector_type(16))) float f32x16;
typedef __attribute__((ext_vector_type(8))) short bf16x8;   // 8 bf16 (4 VGPRs)
typedef __attribute__((ext_vector_type(4))) float float4v;
typedef __attribute__((ext_vector_type(4))) unsigned short u16x4;
typedef __attribute__((ext_vector_type(8))) unsigned short u16x8;

__device__ __forceinline__ float bf2f(u16 u) { return __uint_as_float(((u32)u) << 16); }
__device__ __forceinline__ u16 f2bf(float f) {
  u32 x = __float_as_uint(f);
  x += 0x7fffu + ((x >> 16) & 1u);   // RNE; values here are finite
  return (u16)(x >> 16);
}
__device__ __forceinline__ u32 cvtpk(float lo, float hi_) {  // [lo | hi] bf16 pair
  u32 r;
  asm("v_cvt_pk_bf16_f32 %0, %1, %2" : "=v"(r) : "v"(lo), "v"(hi_));
  return r;
}

__device__ __forceinline__ void gll16(const void* g, void* l) {
  __builtin_amdgcn_global_load_lds((const __attribute__((address_space(1))) void*)g,
                                   (__attribute__((address_space(3))) void*)l, 16, 0, 0);
}

#define MFMA_BF16(a, b, c) __builtin_amdgcn_mfma_f32_16x16x32_bf16((a), (b), (c), 0, 0, 0)
#define MFMA32(a, b, c) __builtin_amdgcn_mfma_f32_32x32x16_bf16((a), (b), (c), 0, 0, 0)

#define BARRIER() __builtin_amdgcn_s_barrier()
#define LGKM0() do { asm volatile("s_waitcnt lgkmcnt(0)" ::: "memory"); \
                     __builtin_amdgcn_sched_barrier(0); } while (0)
#define VMCNT(n) do { asm volatile("s_waitcnt vmcnt(" #n ")" ::: "memory"); \
                      __builtin_amdgcn_sched_barrier(0); } while (0)

// ------------------------------- cast fp32 -> bf16 -------------------------------
__global__ __launch_bounds__(256) void cast_kernel(const float* __restrict__ src,
                                                   u16* __restrict__ dst, int n) {
  const int stride = gridDim.x * 256 * 4;
  for (int i = (blockIdx.x * 256 + threadIdx.x) * 4; i < n; i += stride) {
    const float4v v = *(const float4v*)(src + i);
    u16x4 o;
    o[0] = f2bf(v[0]); o[1] = f2bf(v[1]); o[2] = f2bf(v[2]); o[3] = f2bf(v[3]);
    *(u16x4*)(dst + i) = o;
  }
}

// ------------------------------- rope tables -------------------------------
__global__ __launch_bounds__(256) void rope_tables(float* __restrict__ cosd,
                                                   float* __restrict__ sind) {
  const int idx = blockIdx.x * 256 + threadIdx.x;   // 2048*64
  const int t = idx >> 6, j = idx & 63;
  const float inv = powf(10000.0f, -(float)(j & 31) * (1.0f / 32.0f));
  const float ang = (float)t * inv;
  cosd[idx] = cosf(ang);
  sind[idx] = sinf(ang);
}

// ------------------------------- GEMM 256x256 8-phase (C = A * B^T) -------------------------------
__device__ __forceinline__ void store_out(float* C, size_t i, float v) { C[i] = v; }
__device__ __forceinline__ void store_out(u16* C, size_t i, float v) { C[i] = f2bf(v); }

#define PH_MFMA(MG, NG)                                                          \
  do {                                                                           \
    _Pragma("unroll") for (int i_ = 0; i_ < 4; ++i_)                             \
      _Pragma("unroll") for (int jn_ = 0; jn_ < 2; ++jn_)                        \
        _Pragma("unroll") for (int ks_ = 0; ks_ < 2; ++ks_)                      \
          acc[(MG) * 4 + i_][(NG) * 2 + jn_] =                                   \
              MFMA_BF16(af[i_][ks_], bfr[jn_][ks_],                              \
                        acc[(MG) * 4 + i_][(NG) * 2 + jn_]);                     \
  } while (0)

template <typename OutT>
__global__ __launch_bounds__(512, 2) void gemm_bt8(const u16* __restrict__ A,
                                                   const u16* __restrict__ B,
                                                   OutT* __restrict__ C, int M, int N, int K,
                                                   int lda, int ldb, int ldc) {
  __shared__ __align__(16) u16 LDS[2][2][2][128 * 64];  // [buf][A=0/B=1][half][128x64]
  const int nbn = N >> 8;
  const int nwg = gridDim.x;                       // divisible by 8 for our shapes
  const int wg = (blockIdx.x & 7) * (nwg >> 3) + (blockIdx.x >> 3);  // XCD swizzle (T1)
  const int bm = wg / nbn, bn = wg % nbn;
  const int tid = threadIdx.x;
  const int w = tid >> 6, l = tid & 63, l15 = l & 15, l4 = l >> 4;
  const int wr = w >> 2, wc = w & 3;               // 2 M-warps x 4 N-warps
  const u16* Abase = A + (size_t)bm * 256 * lda;
  const u16* Bbase = B + (size_t)bn * 256 * ldb;
  const int NT = K >> 6;

  f32x4 acc[8][4] = {};
  bf16x8 af[4][2], bfr[2][2];

  auto STAGE = [&](int sel, int h, int t) {
    const u16* src = (sel ? Bbase + (size_t)h * 128 * ldb : Abase + (size_t)h * 128 * lda) +
                     t * 64;
    const int ld = sel ? ldb : lda;
    char* dst = (char*)&LDS[t & 1][sel][h][0];
#pragma unroll
    for (int j = 0; j < 2; ++j) {
      const int o = j * 8192 + tid * 16;
      const int r = o >> 7;
      const int cb = (o & 127) ^ ((r & 7) << 4);
      gll16(src + (size_t)r * ld + (cb >> 1), dst + o);
    }
  };
  auto LDA_ = [&](int bb, int mg) {
    const char* base = (const char*)&LDS[bb][0][mg][0];
#pragma unroll
    for (int i = 0; i < 4; ++i) {
      const int R = i * 32 + wr * 16 + l15;
#pragma unroll
      for (int ks = 0; ks < 2; ++ks)
        af[i][ks] = *(const bf16x8*)(base + R * 128 + ((ks * 64 + l4 * 16) ^ ((R & 7) << 4)));
    }
  };
  auto LDB_ = [&](int bb, int ng) {
    const char* base = (const char*)&LDS[bb][1][ng][0];
#pragma unroll
    for (int jn = 0; jn < 2; ++jn) {
      const int R = jn * 64 + wc * 16 + l15;
#pragma unroll
      for (int ks = 0; ks < 2; ++ks)
        bfr[jn][ks] = *(const bf16x8*)(base + R * 128 + ((ks * 64 + l4 * 16) ^ ((R & 7) << 4)));
    }
  };

  STAGE(0, 0, 0); STAGE(1, 0, 0); STAGE(0, 1, 0); STAGE(1, 1, 0);
  if (NT > 1) { STAGE(1, 0, 1); STAGE(0, 1, 1); STAGE(1, 1, 1); }
  VMCNT(6);
  BARRIER();

  for (int T = 0; T < NT; ++T) {
    const int bb = T & 1;
    LDA_(bb, 0); LDB_(bb, 0);
    if (T + 1 < NT) STAGE(0, 0, T + 1);
    BARRIER(); LGKM0();
    __builtin_amdgcn_s_setprio(1); PH_MFMA(0, 0); __builtin_amdgcn_s_setprio(0);
    BARRIER();
    LDA_(bb, 1);
    if (T + 2 < NT) STAGE(1, 0, T + 2);
    BARRIER(); LGKM0();
    __builtin_amdgcn_s_setprio(1); PH_MFMA(1, 0); __builtin_amdgcn_s_setprio(0);
    BARRIER();
    LDB_(bb, 1);
    if (T + 2 < NT) STAGE(0, 1, T + 2);
    BARRIER(); LGKM0();
    __builtin_amdgcn_s_setprio(1); PH_MFMA(1, 1); __builtin_amdgcn_s_setprio(0);
    BARRIER();
    LDA_(bb, 0);
    if (T + 2 < NT) STAGE(1, 1, T + 2);
    BARRIER(); LGKM0();
    __builtin_amdgcn_s_setprio(1); PH_MFMA(0, 1); __builtin_amdgcn_s_setprio(0);
    if (T + 2 < NT) { VMCNT(6); } else { VMCNT(0); }
    BARRIER();
  }

#pragma unroll
  for (int mf = 0; mf < 8; ++mf) {
    const int mg = mf >> 2, i = mf & 3;
    const int row0 = bm * 256 + mg * 128 + i * 32 + wr * 16 + l4 * 4;
#pragma unroll
    for (int f = 0; f < 4; ++f) {
      const int col = bn * 256 + f * 64 + wc * 16 + l15;
#pragma unroll
      for (int rr = 0; rr < 4; ++rr)
        store_out(C, (size_t)(row0 + rr) * ldc + col, acc[mf][f][rr]);
    }
  }
}

// ------------------------------- rope apply (in place on qkvb) -------------------------------
__global__ __launch_bounds__(256) void rope_apply_inplace(u16* __restrict__ qkvb,
                                                          const float* __restrict__ cosd,
                                                          const float* __restrict__ sind) {
  const int wid = blockIdx.x * 4 + (threadIdx.x >> 6);  // 8192*16 waves
  const int j = threadIdx.x & 63;
  const int h = wid & 15;
  const int m = wid >> 4;
  const int s = m & 2047;
  const float c = cosd[s * 64 + j];
  const float sn = sind[s * 64 + j];
  u16* qp = qkvb + (size_t)m * 6144 + h * 128;
  u16* kp = qp + 2048;
  const u32 qv = *(const u32*)(qp + 2 * j);
  const u32 kv = *(const u32*)(kp + 2 * j);
  const float q1 = bf2f((u16)(qv & 0xffff)), q2 = bf2f((u16)(qv >> 16));
  const float k1 = bf2f((u16)(kv & 0xffff)), k2 = bf2f((u16)(kv >> 16));
  qp[j]      = f2bf(q1 * c - q2 * sn);
  qp[64 + j] = f2bf(q1 * sn + q2 * c);
  kp[j]      = f2bf(k1 * c - k2 * sn);
  kp[64 + j] = f2bf(k1 * sn + k2 * c);
}

// ------------------------------- V transpose -------------------------------
__global__ __launch_bounds__(256) void v_transpose(const u16* __restrict__ qkvb,
                                                   u16* __restrict__ vt) {
  __shared__ u16 tile[64][130];                    // +2 pad
  const int st = blockIdx.x & 31, bh = blockIdx.x >> 5;
  const int b = bh >> 4, h = bh & 15;
  const int tid = threadIdx.x;
#pragma unroll
  for (int p = 0; p < 4; ++p) {                    // read 64x128, coalesced
    const int ss = p * 16 + (tid >> 4);
    const int d0 = (tid & 15) * 8;
    const u16x8 v = *(const u16x8*)(qkvb + (size_t)(b * 2048 + st * 64 + ss) * 6144 +
                                    4096 + h * 128 + d0);
#pragma unroll
    for (int i = 0; i < 8; ++i) tile[ss][d0 + i] = v[i];
  }
  __syncthreads();
#pragma unroll
  for (int p = 0; p < 4; ++p) {                    // write 128x64, coalesced
    const int d = p * 32 + (tid >> 3);
    const int s0 = (tid & 7) * 8;
    u16x8 ov;
#pragma unroll
    for (int i = 0; i < 8; ++i) ov[i] = tile[s0 + i][d];
    *(u16x8*)(vt + (size_t)(bh * 128 + d) * 2048 + st * 64 + s0) = ov;
  }
}

// ------------------------------- flash attention (8-wave, 32x32, swapped-QK^T) -------------------------------
// grid(x=bh=64, y=8). Block q-range = qt*256..+256 (qt = 7-y, heavy-first).
// Wave w owns 32 q-rows. S^T = mfma(K, Q): lane holds S[q=l&31][32 keys in regs] ->
// softmax fully in-register (one lane^32 exchange). O^T = mfma(V^T, P^T) keeps the
// alpha-rescale lane-local. Epilogue transposes O^T via LDS, writes y over q-cols of qkvb.
__global__ __launch_bounds__(512, 2) void flash_attn(u16* __restrict__ qkvb,
                                                     const u16* __restrict__ vt) {
  __shared__ __align__(16) char smem[65536];  // K dbuf [2][64][128] | V dbuf [2][128][64]
  const int bh = blockIdx.x;
  const int qt = 7 - blockIdx.y;
  const int b = bh >> 4, h = bh & 15;
  const int tid = threadIdx.x;
  const int w = tid >> 6, l = tid & 63;
  const int l31 = l & 31, hi = l >> 5;

  const int q0 = qt * 256 + w * 32;           // wave's first q row
  const int qg = q0 + l31;                    // this lane's q (S^T column)

  // Q fragments: B-operand of QK^T: Q[qg][ds*16 + hi*8 + i]
  bf16x8 qf[8];
  {
    const u16* Qrow = qkvb + (size_t)(b * 2048 + qg) * 6144 + h * 128 + hi * 8;
#pragma unroll
    for (int d = 0; d < 8; ++d) qf[d] = *(const bf16x8*)(Qrow + d * 16);
  }

  f32x16 ot[4];
#pragma unroll
  for (int dt = 0; dt < 4; ++dt) ot[dt] = 0.f;
  float mrun = -1e30f, lrun = 0.f;

  const int NT = 4 * qt + 4;
  const u16* Kg0 = qkvb + (size_t)b * 2048 * 6144 + 2048 + h * 128;  // + key*6144
  const u16* Vg0 = vt + (size_t)bh * 128 * 2048;                      // + d*2048 + key

  auto STAGE = [&](int t) {
    const u16* Kg = Kg0 + (size_t)t * 64 * 6144;
    const u16* Vg = Vg0 + t * 64;
    char* kd = smem + (t & 1) * 16384;
    char* vd = smem + 32768 + (t & 1) * 16384;
#pragma unroll
    for (int j = 0; j < 2; ++j) {
      const int o = j * 8192 + tid * 16;
      {  // K tile [64][128] u16, 256B rows, 4-bit swizzle
        const int r = o >> 8;
        const int cb = (o & 255) ^ ((r & 15) << 4);
        gll16(Kg + (size_t)r * 6144 + (cb >> 1), kd + o);
      }
      {  // V^T tile [128][64] u16, 128B rows, 3-bit swizzle
        const int r = o >> 7;
        const int cb = (o & 127) ^ ((r & 7) << 4);
        gll16(Vg + (size_t)r * 2048 + (cb >> 1), vd + o);
      }
    }
  };

  STAGE(0);
  VMCNT(0);
  BARRIER();

  for (int kt = 0; kt < NT; ++kt) {
    if (kt + 1 < NT) STAGE(kt + 1);

    if (kt * 64 <= q0 + 31) {  // wave-uniform: tile has unmasked keys for this wave
      const char* Kb = smem + (kt & 1) * 16384;
      const char* Vb = smem + 32768 + (kt & 1) * 16384;

      // ---- S^T[key][q] = K x Q^T ----
      f32x16 sa[2];
      sa[0] = 0.f; sa[1] = 0.f;
#pragma unroll
      for (int ks2 = 0; ks2 < 2; ++ks2) {
        const int R = ks2 * 32 + l31;
#pragma unroll
        for (int d = 0; d < 8; ++d) {
          const bf16x8 kf = *(const bf16x8*)(Kb + R * 256 +
                                             ((d * 32 + hi * 16) ^ ((R & 15) << 4)));
          sa[ks2] = MFMA32(kf, qf[d], sa[ks2]);
        }
      }

      // ---- scale + mask + tile max (in-register; lane owns q=qg, 32 keys) ----
      const float SCALE = 0.08838834764831845f;
      float tmax = -1e30f;
      if (kt * 64 + 63 > q0) {  // diagonal tile: mask needed
#pragma unroll
        for (int ks2 = 0; ks2 < 2; ++ks2)
#pragma unroll
          for (int rg = 0; rg < 16; ++rg) {
            const int key = kt * 64 + ks2 * 32 + (rg & 3) + 8 * (rg >> 2) + 4 * hi;
            float sv = sa[ks2][rg] * SCALE;
            sv = (key > qg) ? -1e30f : sv;
            sa[ks2][rg] = sv;
            tmax = fmaxf(tmax, sv);
          }
      } else {
#pragma unroll
        for (int ks2 = 0; ks2 < 2; ++ks2)
#pragma unroll
          for (int rg = 0; rg < 16; ++rg) {
            const float sv = sa[ks2][rg] * SCALE;
            sa[ks2][rg] = sv;
            tmax = fmaxf(tmax, sv);
          }
      }
      tmax = fmaxf(tmax, __shfl_xor(tmax, 32));

      // ---- online softmax update ----
      const float mnew = fmaxf(mrun, tmax);
      const float alpha = __expf(mrun - mnew);
      mrun = mnew;
      float rsum = 0.f;
#pragma unroll
      for (int ks2 = 0; ks2 < 2; ++ks2)
#pragma unroll
        for (int rg = 0; rg < 16; ++rg) {
          const float pv = __expf(sa[ks2][rg] - mnew);
          sa[ks2][rg] = pv;
          rsum += pv;
        }
      rsum += __shfl_xor(rsum, 32);
      lrun = lrun * alpha + rsum;
#pragma unroll
      for (int dt = 0; dt < 4; ++dt)
#pragma unroll
        for (int rg = 0; rg < 16; ++rg) ot[dt][rg] *= alpha;

      // ---- P^T B-fragments: pack bf16 + lane^32 exchange of 4-key quads ----
      // lane(hi) owns quads (g, hi): keys ks2*32 + 8g + 4hi + [0,4)
      // kstep t needs keys t*16 + hi*8 + [0,8) = quads (g*=2(t&1)+hi, hi'=0) , (g*, hi'=1)
      bf16x8 pfrag[4];
#pragma unroll
      for (int t = 0; t < 4; ++t) {
        const int ks2 = t >> 1;
        const int gA = 2 * (t & 1);        // static
        const int gB = gA + 1;             // static
        const u32 a0 = cvtpk(sa[ks2][gA * 4 + 0], sa[ks2][gA * 4 + 1]);
        const u32 a1 = cvtpk(sa[ks2][gA * 4 + 2], sa[ks2][gA * 4 + 3]);
        const u32 b0 = cvtpk(sa[ks2][gB * 4 + 0], sa[ks2][gB * 4 + 1]);
        const u32 b1 = cvtpk(sa[ks2][gB * 4 + 2], sa[ks2][gB * 4 + 3]);
        const u32 snd0 = hi ? a0 : b0;
        const u32 snd1 = hi ? a1 : b1;
        const u32 rcv0 = (u32)__shfl_xor((int)snd0, 32);
        const u32 rcv1 = (u32)__shfl_xor((int)snd1, 32);
        union { u32 u[4]; bf16x8 v; } pk;
        pk.u[0] = hi ? rcv0 : a0;
        pk.u[1] = hi ? rcv1 : a1;
        pk.u[2] = hi ? b0 : rcv0;
        pk.u[3] = hi ? b1 : rcv1;
        pfrag[t] = pk.v;
      }

      // ---- O^T[d][q] += V^T x P^T ----
#pragma unroll
      for (int dt = 0; dt < 4; ++dt) {
        const int R = dt * 32 + l31;
#pragma unroll
        for (int t = 0; t < 4; ++t) {
          const bf16x8 vf = *(const bf16x8*)(Vb + R * 128 +
                                             ((t * 32 + hi * 16) ^ ((R & 7) << 4)));
          ot[dt] = MFMA32(vf, pfrag[t], ot[dt]);
        }
      }
    }

    VMCNT(0);
    BARRIER();
  }

  // ---- epilogue: O^T -> LDS (per-wave 8KB, swizzled) -> coalesced global y ----
  const float inv = 1.0f / lrun;
  char* E = smem + w * 8192;  // [32 q][128 d] u16, 256B rows, 4-bit swizzle
#pragma unroll
  for (int dt = 0; dt < 4; ++dt)
#pragma unroll
    for (int rp = 0; rp < 8; ++rp) {
      const int rg = 2 * rp;
      const int d0 = dt * 32 + (rg & 3) + 8 * (rg >> 2) + 4 * hi;
      const u32 pkv = cvtpk(ot[dt][rg] * inv, ot[dt][rg + 1] * inv);
      *(u32*)(E + l31 * 256 + ((d0 * 2) ^ ((l31 & 15) << 4))) = pkv;
    }
#pragma unroll
  for (int p = 0; p < 8; ++p) {
    const int q = p * 4 + (l >> 4);
    const int c = l & 15;
    const bf16x8 vv = *(const bf16x8*)(E + q * 256 + ((c * 16) ^ ((q & 15) << 4)));
    *(bf16x8*)(qkvb + (size_t)(b * 2048 + q0 + q) * 6144 + h * 128 + c * 8) = vv;
  }
}

// ------------------------------- launch -------------------------------
extern "C" void kernel_launch(void* const* d_in, const int* in_sizes, int n_in,
                              void* d_out, int out_size, void* d_ws, size_t ws_size,
                              hipStream_t stream) {
  const float* x     = (const float*)d_in[0];
  // d_in[1] = mask (causal, implemented analytically)
  const float* w_qkv = (const float*)d_in[2];
  const float* w_out = (const float*)d_in[3];
  float* out = (float*)d_out;
  char* ws = (char*)d_ws;

  // Peak workspace: 161 MB
  u16* woutb = (u16*)(ws);                          // [0,8) MB, live till GEMM2
  u16* xb    = (u16*)(ws + ((size_t)8 << 20));      // [8,40), dead after GEMM1
  u16* vt    = (u16*)(ws + ((size_t)8 << 20));      // [8,40), written after GEMM1
  u16* wqkvb = (u16*)(ws + ((size_t)40 << 20));     // [40,64), dead after GEMM1
  u16* qkvb  = (u16*)(ws + ((size_t)64 << 20));     // [64,160); y lands in q-cols
  float* cosd = (float*)(ws + ((size_t)160 << 20)); // 0.5 MB
  float* sind = (float*)(ws + ((size_t)160 << 20) + ((size_t)1 << 19));

  cast_kernel<<<2048, 256, 0, stream>>>(x, xb, 8192 * 2048);
  cast_kernel<<<2048, 256, 0, stream>>>(w_qkv, wqkvb, 6144 * 2048);
  cast_kernel<<<1024, 256, 0, stream>>>(w_out, woutb, 2048 * 2048);
  rope_tables<<<512, 256, 0, stream>>>(cosd, sind);
  gemm_bt8<u16><<<768, 512, 0, stream>>>(xb, wqkvb, qkvb, 8192, 6144, 2048,
                                         2048, 2048, 6144);
  rope_apply_inplace<<<32768, 256, 0, stream>>>(qkvb, cosd, sind);
  v_transpose<<<2048, 256, 0, stream>>>(qkvb, vt);
  flash_attn<<<dim3(64, 8), 512, 0, stream>>>(qkvb, vt);
  gemm_bt8<float><<<256, 512, 0, stream>>>(qkvb, woutb, out, 8192, 2048, 2048,
                                           6144, 2048, 2048);
}